// Round 5
// baseline (1314.213 us; speedup 1.0000x reference)
//
#include <hip/hip_runtime.h>

#define T_ 512
#define B_ 256
#define H_ 256
#define DIN_ 64

typedef __attribute__((ext_vector_type(8))) short short8;
typedef __attribute__((ext_vector_type(4))) float f32x4;
typedef __attribute__((ext_vector_type(4))) unsigned int u32x4;

__device__ __forceinline__ unsigned short f2bf(float f) {
  unsigned u = __float_as_uint(f);
  u += 0x7FFFu + ((u >> 16) & 1u);   // RNE
  return (unsigned short)(u >> 16);
}
__device__ __forceinline__ float bf2f(unsigned short s) {
  return __uint_as_float(((unsigned)s) << 16);
}
__device__ __forceinline__ float sigm(float x) { return 1.0f / (1.0f + __expf(-x)); }
__device__ __forceinline__ float tanh_(float x) {
  float xx = fminf(fmaxf(x, -30.0f), 30.0f);
  float e = __expf(2.0f * xx);
  return (e - 1.0f) / (e + 1.0f);
}

// 1x dwordx4 load with sc1 (agent scope): bypasses L1 (and non-agent-coherent
// L2) -> reads LLC-fresh data. Proven instruction class (R0/R4's poll used
// 4 of these back-to-back); "=&v" so the result quad never aliases the
// address pair across retry iterations.
__device__ __forceinline__ void load4_sc1(const unsigned* p, u32x4& a) {
  asm volatile(
      "global_load_dwordx4 %0, %1, off sc1\n\t"
      "s_waitcnt vmcnt(0)"
      : "=&v"(a)
      : "v"(p) : "memory");
}

__device__ __forceinline__ bool tags_ok1(u32x4 a, unsigned w) {
  unsigned m = (a.x >> 16) ^ w; m |= (a.y >> 16) ^ w;
  m |= (a.z >> 16) ^ w;         m |= (a.w >> 16) ^ w;
  return m == 0;
}

// Grid: 64 wgs x 1024 threads (16 waves). wgid = gq*16 + gb:
//   gb = wgid & 15 (batch group, 16 rows), gq = wgid >> 4 (h-col quarter,
//   64 cols). Exchange group = {gb, gb+16, gb+32, gb+48}: 4 peers (was 16),
//   all === gb mod 8 -> same XCD under round-robin dispatch (perf-only;
//   correctness is agent-scope sc1, identical protocol to the proven R0).
//
// This is FOUR R0 wgs fused into one 1024-thread wg. Per-wave code is R0's
// verbatim: wave wv -> gate g=wv&3, col-block hb=wv>>2; one 16x16 MFMA tile,
// bh[8]/bx[2] VGPR-resident, gbuf round-trip, elementwise cell (1 cell per
// thread), 1 publish dword per thread, 2 barriers per step. Poll = 1 tagged
// dwordx4 per thread (1024 threads x 4 dwords = all 16x256 entries).
//
// h exchange element = (step_tag << 16) | bf16(h); parity double-buffered.
// Safety invariant (unchanged from R0): wg X stores tag s+1 (clobbering its
// s-1 entry) only after X acquired ALL of s (barriers B,C order acquire
// before publish within the step); each peer published s only after fully
// acquiring s-1; so every reader of the s-1 entry finished before the
// clobber. The load IS the poll; stores are fire-and-forget. ws re-poisoned
// to 0xAA each launch -> initial tag 0xAAAA never matches.
__global__ __launch_bounds__(1024) void lstm_kern(
    const float* __restrict__ xin, const float* __restrict__ h0f,
    const float* __restrict__ c0f, const float* __restrict__ Wih,
    const float* __restrict__ Whh, const float* __restrict__ bias,
    const float* __restrict__ Wout, const float* __restrict__ bout,
    float* __restrict__ out, unsigned* hbuf32)
{
  const int tid = threadIdx.x;
  const int gb  = blockIdx.x & 15;   // batch group
  const int gq  = blockIdx.x >> 4;   // h-col quarter (64 cols)
  const int wv  = tid >> 6;          // 16 waves
  const int ln  = tid & 63;
  const int g   = wv & 3;            // gate type (i,f,g,o)
  const int hb  = wv >> 2;           // col-block within quarter (16 cols)
  const int colB = ln & 15;          // MFMA n / A-row m
  const int krow = ln >> 4;          // MFMA k-quad

  __shared__ unsigned short h_s[16 * 264];  // 16 rows x 256 bf16, pitch 264
  __shared__ unsigned short x_s[16 * 72];   // 16 rows x 64  bf16, pitch 72
  __shared__ float gbuf[4 * 16 * 68];       // [gate][row][64 cols + 4 pad]

  // ---- W fragments (B-operand layout: lane holds W[j][k=krow*8+i]) ----
  const int j = g * H_ + gq * 64 + hb * 16 + colB;   // row in [0,4H)
  short8 bh[8], bx[2];
  #pragma unroll
  for (int kc = 0; kc < 8; ++kc) {
    const float* p = Whh + j * H_ + kc * 32 + krow * 8;
    short8 f;
    #pragma unroll
    for (int i = 0; i < 8; ++i) f[i] = (short)f2bf(p[i]);
    bh[kc] = f;
  }
  #pragma unroll
  for (int kc = 0; kc < 2; ++kc) {
    const float* p = Wih + j * DIN_ + kc * 32 + krow * 8;
    short8 f;
    #pragma unroll
    for (int i = 0; i < 8; ++i) f[i] = (short)f2bf(p[i]);
    bx[kc] = f;
  }
  const float bval = bias[j];

  // elementwise mapping: thread owns (row er, h-col gq*64+ec)
  const int er = tid >> 6, ec = tid & 63;
  const int grow = gb * 16 + er;
  const int gcol = gq * 64 + ec;
  float c_val = c0f[grow * H_ + gcol];
  float h_val = 0.0f;

  // ---- x prefetch: one float4/thread for tid<256, ONE STEP AHEAD ----
  const int xr = tid >> 4, xd = (tid & 15) * 4;     // valid for tid<256
  const float* xrow = xin + (gb * 16 + (xr & 15)) * (T_ * DIN_) + xd;
  float4 xcur{};
  if (tid < 256) xcur = *(const float4*)(xrow);     // x for s=1 (t=0)

  // hbuf32[2 parity][16 groups][16 rows][256 cols] dwords
  const int hr  = tid >> 6;           // poll row (== er)
  const int hcb = (tid & 63) * 4;     // poll col base (4 dwords)
  const unsigned* ldp_base = hbuf32 + gb * 4096 + hr * 256 + hcb;
  unsigned* stp_base = hbuf32 + gb * 4096 + er * 256 + gcol;

  for (int s = 1; s <= T_; ++s) {
    // ---- stage x_{s-1} from prefetch reg; issue next load before the poll ----
    if (tid < 256) {
      unsigned short* q = &x_s[xr * 72 + xd];
      q[0] = f2bf(xcur.x); q[1] = f2bf(xcur.y);
      q[2] = f2bf(xcur.z); q[3] = f2bf(xcur.w);
      const int tn = (s < T_) ? s : (T_ - 1);   // clamped tail load, unused
      xcur = *(const float4*)(xrow + tn * DIN_);
    }

    // ---- acquire h^(s-1): tag-validated sc1 load (the load IS the poll) ----
    if (s == 1) {
      int r = tid >> 6, c4 = tid & 63;
      float4 v = ((const float4*)(h0f + (gb * 16 + r) * H_))[c4];
      unsigned short* q = &h_s[r * 264 + c4 * 4];
      q[0] = f2bf(v.x); q[1] = f2bf(v.y); q[2] = f2bf(v.z); q[3] = f2bf(v.w);
    } else {
      const unsigned want = (unsigned)(s - 1);
      const unsigned* ldp = ldp_base + (((s - 1) & 1) << 16);  // parity buffer
      u32x4 va;
      int tries = 0;
      do {
        load4_sc1(ldp, va);
        if (tags_ok1(va, want)) break;
      } while (++tries < (1 << 18));   // hang guard (unreachable per invariant)
      unsigned* q32 = (unsigned*)&h_s[hr * 264 + hcb];
      q32[0] = (va.x & 0xFFFFu) | (va.y << 16);
      q32[1] = (va.z & 0xFFFFu) | (va.w << 16);
    }
    __syncthreads();   // (B) x_s + h_s staged

    // ---- gates tile: D[batch m][gate col n], K = 64 (x) + 256 (h) ----
    f32x4 acc = {0.f, 0.f, 0.f, 0.f};
    #pragma unroll
    for (int kc = 0; kc < 2; ++kc) {
      short8 a = *(const short8*)&x_s[colB * 72 + kc * 32 + krow * 8];
      acc = __builtin_amdgcn_mfma_f32_16x16x32_bf16(a, bx[kc], acc, 0, 0, 0);
    }
    #pragma unroll
    for (int kc = 0; kc < 8; ++kc) {
      short8 a = *(const short8*)&h_s[colB * 264 + kc * 32 + krow * 8];
      acc = __builtin_amdgcn_mfma_f32_16x16x32_bf16(a, bh[kc], acc, 0, 0, 0);
    }
    #pragma unroll
    for (int i = 0; i < 4; ++i)   // D layout: col=lane&15, row=quad*4+i
      gbuf[g * 1088 + (krow * 4 + i) * 68 + hb * 16 + colB] = acc[i] + bval;
    __syncthreads();   // (C)

    // ---- elementwise LSTM cell update ----
    float gi = gbuf[0 * 1088 + er * 68 + ec];
    float gf = gbuf[1 * 1088 + er * 68 + ec];
    float gg = gbuf[2 * 1088 + er * 68 + ec];
    float go = gbuf[3 * 1088 + er * 68 + ec];
    c_val = sigm(gf) * c_val + sigm(gi) * tanh_(gg);
    h_val = sigm(go) * tanh_(c_val);

    // ---- publish: fire-and-forget tagged sc1 store into parity buffer ----
    unsigned pk = ((unsigned)s << 16) | (unsigned)f2bf(h_val);
    __hip_atomic_store(stp_base + ((s & 1) << 16), pk,
                       __ATOMIC_RELAXED, __HIP_MEMORY_SCOPE_AGENT);
  }

  // ---- outputs: rnn_outputs | logits | h | c ----
  out[grow * H_ + gcol] = h_val;                 // out0: rnn_outputs
  out[67584 + grow * H_ + gcol] = h_val;         // out2: h   (65536+2048)
  out[133120 + grow * H_ + gcol] = c_val;        // out3: c

  if (gq == 0) {  // logits for this batch group: need full h^T rows
    const unsigned want = (unsigned)T_;
    const unsigned* ldp = ldp_base + ((T_ & 1) << 16);
    u32x4 va;
    int tries = 0;
    do {
      load4_sc1(ldp, va);
      if (tags_ok1(va, want)) break;
    } while (++tries < (1 << 18));
    unsigned* q32 = (unsigned*)&h_s[hr * 264 + hcb];
    q32[0] = (va.x & 0xFFFFu) | (va.y << 16);
    q32[1] = (va.z & 0xFFFFu) | (va.w << 16);
    __syncthreads();
    if (tid < 128) {
      int r = tid >> 3, o = tid & 7;
      float a = bout[o];
      for (int k = 0; k < H_; ++k)
        a = fmaf(bf2f(h_s[r * 264 + k]), Wout[o * H_ + k], a);
      out[65536 + (gb * 16 + r) * 8 + o] = a;   // out1: logits
    }
  }
}

extern "C" void kernel_launch(void* const* d_in, const int* in_sizes, int n_in,
                              void* d_out, int out_size, void* d_ws, size_t ws_size,
                              hipStream_t stream) {
  const float* xin  = (const float*)d_in[0];
  const float* h0f  = (const float*)d_in[1];
  const float* c0f  = (const float*)d_in[2];
  const float* Wih  = (const float*)d_in[3];
  const float* Whh  = (const float*)d_in[4];
  const float* bias = (const float*)d_in[5];
  const float* Wout = (const float*)d_in[6];
  const float* bout = (const float*)d_in[7];
  float* out = (float*)d_out;

  // ws: hbuf32[2][16][16][256] dwords (512 KiB)
  unsigned* hbuf32 = (unsigned*)d_ws;

  void* args[] = {&xin, &h0f, &c0f, &Wih, &Whh, &bias, &Wout, &bout,
                  &out, &hbuf32};
  hipLaunchCooperativeKernel((void*)lstm_kern, dim3(64), dim3(1024),
                             args, 0, stream);
}